// Round 1
// baseline (3952.517 us; speedup 1.0000x reference)
//
#include <hip/hip_runtime.h>

// GCN: out = GCN2(relu(GCN1(x))) @ Wfc + bfc
// Linearity trick: segment_sum((x@W)[src]*norm) == segment_sum(x[src]*norm) @ W
//  -> layer1 scatters 2 feats (not 16), layer2 applies W2 first and scatters 8.
//
// ws layout (floats): [0,N) deg->dinv | [N,3N) aggx | [3N,11N) agg2 | [11N,19N) h2lin
// (19N floats = 7.6 MB)

__global__ void k_degree(const int* __restrict__ dst, float* __restrict__ deg, int E) {
    int e = blockIdx.x * blockDim.x + threadIdx.x;
    if (e < E) atomicAdd(&deg[dst[e]], 1.0f);
}

__global__ void k_dinv(float* __restrict__ deg_dinv, int N) {
    int i = blockIdx.x * blockDim.x + threadIdx.x;
    if (i < N) deg_dinv[i] = rsqrtf(deg_dinv[i] + 1.0f);
}

// layer-1 scatter of RAW x (2 features) -- linearity lets us defer W1
__global__ void k_scatter1(const int* __restrict__ src, const int* __restrict__ dst,
                           const float* __restrict__ x, const float* __restrict__ dinv,
                           float* __restrict__ aggx, int E) {
    int e = blockIdx.x * blockDim.x + threadIdx.x;
    if (e >= E) return;
    int s = src[e], d = dst[e];
    float norm = dinv[s] * dinv[d];
    float2 xv = *reinterpret_cast<const float2*>(x + 2 * (size_t)s);
    atomicAdd(&aggx[2 * (size_t)d + 0], xv.x * norm);
    atomicAdd(&aggx[2 * (size_t)d + 1], xv.y * norm);
}

// per-node: z = aggx + x*dinv^2 ; h1 = relu(z@W1 + b1) ; h2lin = h1@W2  (store 8 floats)
__global__ void k_node1(const float* __restrict__ x, const float* __restrict__ dinv,
                        const float* __restrict__ aggx,
                        const float* __restrict__ W1, const float* __restrict__ b1,
                        const float* __restrict__ W2,
                        float* __restrict__ h2lin, int N) {
    int i = blockIdx.x * blockDim.x + threadIdx.x;
    if (i >= N) return;
    float dv = dinv[i], dv2 = dv * dv;
    float x0 = x[2 * (size_t)i], x1 = x[2 * (size_t)i + 1];
    float z0 = aggx[2 * (size_t)i] + x0 * dv2;
    float z1 = aggx[2 * (size_t)i + 1] + x1 * dv2;
    float acc[8];
#pragma unroll
    for (int g = 0; g < 8; ++g) acc[g] = 0.0f;
#pragma unroll
    for (int f = 0; f < 16; ++f) {
        float h = fmaf(z0, W1[f], fmaf(z1, W1[16 + f], b1[f]));  // W1 is [2,16] row-major
        h = fmaxf(h, 0.0f);
#pragma unroll
        for (int g = 0; g < 8; ++g) acc[g] = fmaf(h, W2[f * 8 + g], acc[g]);
    }
    float4* o = reinterpret_cast<float4*>(h2lin + 8 * (size_t)i);
    o[0] = make_float4(acc[0], acc[1], acc[2], acc[3]);
    o[1] = make_float4(acc[4], acc[5], acc[6], acc[7]);
}

// layer-2 scatter of h2lin (8 features, W2 already applied)
__global__ void k_scatter2(const int* __restrict__ src, const int* __restrict__ dst,
                           const float* __restrict__ h2lin, const float* __restrict__ dinv,
                           float* __restrict__ agg2, int E) {
    int e = blockIdx.x * blockDim.x + threadIdx.x;
    if (e >= E) return;
    int s = src[e], d = dst[e];
    float norm = dinv[s] * dinv[d];
    const float4* hv = reinterpret_cast<const float4*>(h2lin + 8 * (size_t)s);
    float4 a = hv[0], b = hv[1];
    float* o = agg2 + 8 * (size_t)d;
    atomicAdd(o + 0, a.x * norm);
    atomicAdd(o + 1, a.y * norm);
    atomicAdd(o + 2, a.z * norm);
    atomicAdd(o + 3, a.w * norm);
    atomicAdd(o + 4, b.x * norm);
    atomicAdd(o + 5, b.y * norm);
    atomicAdd(o + 6, b.z * norm);
    atomicAdd(o + 7, b.w * norm);
}

// out[i, :] = (agg2[i] + h2lin[i]*dinv^2 + b2) @ Wfc + bfc
// 8 nodes per block, 256 threads; thread t owns columns 4t..4t+3 (float4 store),
// Wfc held in registers across the 8 nodes.
__global__ void k_final(const float* __restrict__ h2lin, const float* __restrict__ agg2,
                        const float* __restrict__ dinv, const float* __restrict__ b2,
                        const float* __restrict__ Wfc, const float* __restrict__ bfc,
                        float* __restrict__ out, int N, int C) {
    __shared__ float sh[64];  // 8 nodes x 8 feats
    int i0 = blockIdx.x * 8;
    int t = threadIdx.x;
    if (t < 64) {
        int k = t >> 3, f = t & 7;
        int i = i0 + k;
        float v = 0.0f;
        if (i < N) {
            float dv = dinv[i];
            v = agg2[8 * (size_t)i + f] + h2lin[8 * (size_t)i + f] * dv * dv + b2[f];
        }
        sh[t] = v;
    }
    __syncthreads();
    int c4 = t * 4;
    if (c4 + 3 < C + 1) {  // t < C/4 (C=1000 -> t<250)
        if (c4 + 4 <= C) {
            float4 w[8];
#pragma unroll
            for (int f = 0; f < 8; ++f)
                w[f] = *reinterpret_cast<const float4*>(Wfc + (size_t)f * C + c4);
            float4 bias = *reinterpret_cast<const float4*>(bfc + c4);
#pragma unroll 1
            for (int k = 0; k < 8; ++k) {
                int i = i0 + k;
                if (i >= N) break;
                float4 acc = bias;
#pragma unroll
                for (int f = 0; f < 8; ++f) {
                    float hv = sh[k * 8 + f];
                    acc.x = fmaf(hv, w[f].x, acc.x);
                    acc.y = fmaf(hv, w[f].y, acc.y);
                    acc.z = fmaf(hv, w[f].z, acc.z);
                    acc.w = fmaf(hv, w[f].w, acc.w);
                }
                *reinterpret_cast<float4*>(out + (size_t)i * C + c4) = acc;
            }
        }
    }
}

extern "C" void kernel_launch(void* const* d_in, const int* in_sizes, int n_in,
                              void* d_out, int out_size, void* d_ws, size_t ws_size,
                              hipStream_t stream) {
    const float* x   = (const float*)d_in[0];
    const int*   ei  = (const int*)d_in[1];
    const float* W1  = (const float*)d_in[2];
    const float* b1  = (const float*)d_in[3];
    const float* W2  = (const float*)d_in[4];
    const float* b2  = (const float*)d_in[5];
    const float* Wfc = (const float*)d_in[6];
    const float* bfc = (const float*)d_in[7];
    float* out = (float*)d_out;

    const int N = in_sizes[0] / 2;       // x is [N,2]
    const int E = in_sizes[1] / 2;       // edge_index is [2,E]
    const int C = in_sizes[7];           // bfc is [C]
    const int* src = ei;
    const int* dst = ei + E;

    float* ws    = (float*)d_ws;
    float* deg   = ws;                       // [N]   -> becomes dinv in place
    float* aggx  = ws + (size_t)N;           // [2N]
    float* agg2  = ws + 3 * (size_t)N;       // [8N]
    float* h2lin = ws + 11 * (size_t)N;      // [8N]

    // zero the accumulators (deg + aggx + agg2 = 11N floats); ws is poisoned 0xAA
    hipMemsetAsync(ws, 0, 11 * (size_t)N * sizeof(float), stream);

    const int T = 256;
    k_degree  <<<(E + T - 1) / T, T, 0, stream>>>(dst, deg, E);
    k_dinv    <<<(N + T - 1) / T, T, 0, stream>>>(deg, N);
    k_scatter1<<<(E + T - 1) / T, T, 0, stream>>>(src, dst, x, deg, aggx, E);
    k_node1   <<<(N + T - 1) / T, T, 0, stream>>>(x, deg, aggx, W1, b1, W2, h2lin, N);
    k_scatter2<<<(E + T - 1) / T, T, 0, stream>>>(src, dst, h2lin, deg, agg2, E);
    k_final   <<<(N + 7) / 8, T, 0, stream>>>(h2lin, agg2, deg, b2, Wfc, bfc, out, N, C);
}

// Round 2
// 1476.531 us; speedup vs baseline: 2.6769x; 2.6769x over previous
//
#include <hip/hip_runtime.h>

// GCN via CSR gather (atomic-minimized).
// Round-1 finding: device fp32 atomicAdd = ~20 G/s, 32 B HBM write-through per op.
// => replace 70.4M scatter atomics with 12.8M int atomics (count + CSR fill),
//    aggregate with wave-per-node gather-sums over CSR.
// Norm factorization: sum_e h[src]*dinv[src]*dinv[dst] = dinv[dst] * sum_e (h*dinv)[src].

__global__ void k_count(const int* __restrict__ dst, int* __restrict__ cnt, int E) {
    int e = blockIdx.x * blockDim.x + threadIdx.x;
    if (e < E) atomicAdd(&cnt[dst[e]], 1);
}

// Single-workgroup chunked exclusive scan (wave-shuffle based) + dinv + xs = x*dinv.
__global__ void __launch_bounds__(1024) k_scan(
        const int* __restrict__ cnt, int* __restrict__ off, int* __restrict__ cursor,
        float* __restrict__ dinv, const float* __restrict__ x, float* __restrict__ xs, int N) {
    __shared__ int swt[16];
    __shared__ int stot;
    int tid = threadIdx.x;
    int lane = tid & 63, wid = tid >> 6;
    int carry = 0;
    for (int base = 0; base < N; base += 1024) {
        int i = base + tid;
        int v = (i < N) ? cnt[i] : 0;
        int incl = v;
#pragma unroll
        for (int d = 1; d < 64; d <<= 1) {
            int t = __shfl_up(incl, d);
            if (lane >= d) incl += t;
        }
        if (lane == 63) swt[wid] = incl;
        __syncthreads();
        if (tid < 16) {
            int orig = swt[tid];
            int w = orig;
#pragma unroll
            for (int d = 1; d < 16; d <<= 1) {
                int t = __shfl_up(w, d);
                if (tid >= d) w += t;
            }
            swt[tid] = w - orig;      // exclusive prefix of wave totals
            if (tid == 15) stot = w;  // chunk total
        }
        __syncthreads();
        if (i < N) {
            int excl = carry + swt[wid] + incl - v;
            off[i] = excl;
            cursor[i] = excl;
            float dv = rsqrtf((float)v + 1.0f);
            dinv[i] = dv;
            xs[2 * (size_t)i]     = x[2 * (size_t)i] * dv;
            xs[2 * (size_t)i + 1] = x[2 * (size_t)i + 1] * dv;
        }
        carry += stot;
        __syncthreads();  // protect swt/stot before next chunk overwrites
    }
    if (tid == 0) off[N] = carry;
}

__global__ void k_fill(const int* __restrict__ src, const int* __restrict__ dst,
                       int* __restrict__ cursor, int* __restrict__ csr, int E) {
    int e = blockIdx.x * blockDim.x + threadIdx.x;
    if (e >= E) return;
    int d = dst[e];
    int pos = atomicAdd(&cursor[d], 1);
    csr[pos] = src[e];
}

// Wave-per-node: agg of xs (2 feats) -> z -> h1=relu(z@W1+b1) -> h2lin=h1@W2, h2s=h2lin*dinv
__global__ void k_node1(const int* __restrict__ off, const int* __restrict__ csr,
                        const float* __restrict__ xs, const float* __restrict__ x,
                        const float* __restrict__ dinv,
                        const float* __restrict__ W1, const float* __restrict__ b1,
                        const float* __restrict__ W2,
                        float* __restrict__ h2lin, float* __restrict__ h2s, int N) {
    int gid = blockIdx.x * blockDim.x + threadIdx.x;
    int i = gid >> 6, lane = gid & 63;
    if (i >= N) return;
    int beg = off[i], end = off[i + 1];
    float a0 = 0.f, a1 = 0.f;
    for (int e = beg + lane; e < end; e += 64) {
        int s = csr[e];
        float2 v = *reinterpret_cast<const float2*>(xs + 2 * (size_t)s);
        a0 += v.x; a1 += v.y;
    }
#pragma unroll
    for (int d = 32; d > 0; d >>= 1) { a0 += __shfl_xor(a0, d); a1 += __shfl_xor(a1, d); }
    if (lane == 0) {
        float dv = dinv[i], dv2 = dv * dv;
        float z0 = dv * a0 + x[2 * (size_t)i] * dv2;
        float z1 = dv * a1 + x[2 * (size_t)i + 1] * dv2;
        float acc[8];
#pragma unroll
        for (int g = 0; g < 8; ++g) acc[g] = 0.f;
#pragma unroll
        for (int f = 0; f < 16; ++f) {
            float h = fmaf(z0, W1[f], fmaf(z1, W1[16 + f], b1[f]));  // W1 [2,16] row-major
            h = fmaxf(h, 0.f);
#pragma unroll
            for (int g = 0; g < 8; ++g) acc[g] = fmaf(h, W2[f * 8 + g], acc[g]);
        }
        float4* o = reinterpret_cast<float4*>(h2lin + 8 * (size_t)i);
        o[0] = make_float4(acc[0], acc[1], acc[2], acc[3]);
        o[1] = make_float4(acc[4], acc[5], acc[6], acc[7]);
        float4* o2 = reinterpret_cast<float4*>(h2s + 8 * (size_t)i);
        o2[0] = make_float4(acc[0] * dv, acc[1] * dv, acc[2] * dv, acc[3] * dv);
        o2[1] = make_float4(acc[4] * dv, acc[5] * dv, acc[6] * dv, acc[7] * dv);
    }
}

// Wave-per-node: agg of h2s (8 feats) + self-loop + b2 -> zfin
__global__ void k_agg2(const int* __restrict__ off, const int* __restrict__ csr,
                       const float* __restrict__ h2s, const float* __restrict__ h2lin,
                       const float* __restrict__ dinv, const float* __restrict__ b2,
                       float* __restrict__ zfin, int N) {
    int gid = blockIdx.x * blockDim.x + threadIdx.x;
    int i = gid >> 6, lane = gid & 63;
    if (i >= N) return;
    int beg = off[i], end = off[i + 1];
    float a[8];
#pragma unroll
    for (int g = 0; g < 8; ++g) a[g] = 0.f;
    for (int e = beg + lane; e < end; e += 64) {
        int s = csr[e];
        const float4* p = reinterpret_cast<const float4*>(h2s + 8 * (size_t)s);
        float4 u = p[0], w = p[1];
        a[0] += u.x; a[1] += u.y; a[2] += u.z; a[3] += u.w;
        a[4] += w.x; a[5] += w.y; a[6] += w.z; a[7] += w.w;
    }
#pragma unroll
    for (int g = 0; g < 8; ++g) {
#pragma unroll
        for (int d = 32; d > 0; d >>= 1) a[g] += __shfl_xor(a[g], d);
    }
    if (lane == 0) {
        float dv = dinv[i], dv2 = dv * dv;
        const float4* hl = reinterpret_cast<const float4*>(h2lin + 8 * (size_t)i);
        float4 h0 = hl[0], h1v = hl[1];
        float4 r0, r1;
        r0.x = dv * a[0] + h0.x * dv2 + b2[0];
        r0.y = dv * a[1] + h0.y * dv2 + b2[1];
        r0.z = dv * a[2] + h0.z * dv2 + b2[2];
        r0.w = dv * a[3] + h0.w * dv2 + b2[3];
        r1.x = dv * a[4] + h1v.x * dv2 + b2[4];
        r1.y = dv * a[5] + h1v.y * dv2 + b2[5];
        r1.z = dv * a[6] + h1v.z * dv2 + b2[6];
        r1.w = dv * a[7] + h1v.w * dv2 + b2[7];
        float4* o = reinterpret_cast<float4*>(zfin + 8 * (size_t)i);
        o[0] = r0; o[1] = r1;
    }
}

// out[i,:] = zfin[i] @ Wfc + bfc. 8 nodes/block; thread t owns cols 4t..4t+3.
__global__ void k_final(const float* __restrict__ zfin, const float* __restrict__ Wfc,
                        const float* __restrict__ bfc, float* __restrict__ out, int N, int C) {
    __shared__ float sh[64];
    int i0 = blockIdx.x * 8;
    int t = threadIdx.x;
    if (t < 64) {
        int i = i0 + (t >> 3);
        sh[t] = (i < N) ? zfin[8 * (size_t)i + (t & 7)] : 0.f;
    }
    __syncthreads();
    int c4 = t * 4;
    if (c4 + 4 <= C) {
        float4 w[8];
#pragma unroll
        for (int f = 0; f < 8; ++f)
            w[f] = *reinterpret_cast<const float4*>(Wfc + (size_t)f * C + c4);
        float4 bias = *reinterpret_cast<const float4*>(bfc + c4);
#pragma unroll 1
        for (int k = 0; k < 8; ++k) {
            int i = i0 + k;
            if (i >= N) break;
            float4 acc = bias;
#pragma unroll
            for (int f = 0; f < 8; ++f) {
                float hv = sh[k * 8 + f];
                acc.x = fmaf(hv, w[f].x, acc.x);
                acc.y = fmaf(hv, w[f].y, acc.y);
                acc.z = fmaf(hv, w[f].z, acc.z);
                acc.w = fmaf(hv, w[f].w, acc.w);
            }
            *reinterpret_cast<float4*>(out + (size_t)i * C + c4) = acc;
        }
    }
}

extern "C" void kernel_launch(void* const* d_in, const int* in_sizes, int n_in,
                              void* d_out, int out_size, void* d_ws, size_t ws_size,
                              hipStream_t stream) {
    const float* x   = (const float*)d_in[0];
    const int*   ei  = (const int*)d_in[1];
    const float* W1  = (const float*)d_in[2];
    const float* b1  = (const float*)d_in[3];
    const float* W2  = (const float*)d_in[4];
    const float* b2  = (const float*)d_in[5];
    const float* Wfc = (const float*)d_in[6];
    const float* bfc = (const float*)d_in[7];
    float* out = (float*)d_out;

    const int N = in_sizes[0] / 2;  // x is [N,2]
    const int E = in_sizes[1] / 2;  // edge_index is [2,E]
    const int C = in_sizes[7];      // bfc is [C]
    const int* src = ei;
    const int* dst = ei + E;

    // ws layout (all regions padded to 16 elements => 64B alignment)
    size_t NP = (size_t)((N + 16) & ~15);  // >= N+1 for off
    size_t EP = (size_t)((E + 15) & ~15);
    int* off    = (int*)d_ws;      // [NP] (uses N+1)
    int* cnt    = off + NP;        // [NP]
    int* cursor = cnt + NP;        // [NP]
    int* csr    = cursor + NP;     // [EP]
    float* fb    = (float*)(csr + EP);
    float* dinv  = fb;             // [NP]
    float* xs    = dinv + NP;      // [2*NP]
    float* h2lin = xs + 2 * NP;    // [8*NP]
    float* h2s   = h2lin + 8 * NP; // [8*NP]
    float* zfin  = h2s + 8 * NP;   // [8*NP]

    hipMemsetAsync(cnt, 0, NP * sizeof(int), stream);

    const int T = 256;
    k_count<<<(E + T - 1) / T, T, 0, stream>>>(dst, cnt, E);
    k_scan <<<1, 1024, 0, stream>>>(cnt, off, cursor, dinv, x, xs, N);
    k_fill <<<(E + T - 1) / T, T, 0, stream>>>(src, dst, cursor, csr, E);
    {
        int waves_threads = 64;  // one wave per node
        long long tot = (long long)N * waves_threads;
        k_node1<<<(int)((tot + T - 1) / T), T, 0, stream>>>(off, csr, xs, x, dinv, W1, b1, W2,
                                                            h2lin, h2s, N);
        k_agg2 <<<(int)((tot + T - 1) / T), T, 0, stream>>>(off, csr, h2s, h2lin, dinv, b2,
                                                            zfin, N);
    }
    k_final<<<(N + 7) / 8, T, 0, stream>>>(zfin, Wfc, bfc, out, N, C);
}